// Round 1
// baseline (190.367 us; speedup 1.0000x reference)
//
#include <hip/hip_runtime.h>
#include <math.h>

// Problem constants (from reference setup_inputs)
#define PB 8
#define PT 12
#define PN 307
#define PC 64
#define NPAD 320          // padded N for K^T workspace/LDS rows (m up to 319 safe)
#define SCALE 0.35355339059327373f  // 1/sqrt(8) = 1/sqrt(DK)

__device__ __forceinline__ unsigned short f32_to_bf16(float v) {
    unsigned u = __float_as_uint(v);
    u += 0x7FFFu + ((u >> 16) & 1u);   // RNE
    return (unsigned short)(u >> 16);
}
__device__ __forceinline__ float bf16_to_f32(unsigned short h) {
    return __uint_as_float(((unsigned)h) << 16);
}

// ---------------------------------------------------------------------------
// Kernel A: Q/K projection.
//   x:   [B, 64, T, N] fp32
//   Q -> qws [96][307][64] fp32   (row-major, coalesced writes)
//   K -> kws [96][64][NPAD] bf16  (pre-transposed for kernel B, coalesced)
// Grid: 96 (b,t) * 10 chunks of 32 n-rows. Block 256.
// ---------------------------------------------------------------------------
__global__ __launch_bounds__(256) void qk_proj_kernel(
    const float* __restrict__ x,
    const float* __restrict__ Wq, const float* __restrict__ bq,
    const float* __restrict__ Wk, const float* __restrict__ bk,
    float* __restrict__ qws,
    unsigned short* __restrict__ kws)
{
    __shared__ float wqT[64 * 65];   // [c][e], pad 65 -> conflict-free e-reads
    __shared__ float wkT[64 * 68];   // [c][e], pad 68 keeps float4 (e%8==0) aligned
    __shared__ float xs[64][32];     // [c][nl]
    __shared__ float bqs[64], bks[64];

    const int tid = threadIdx.x;
    const int chunk = blockIdx.x % 10;
    const int bt = blockIdx.x / 10;
    const int b = bt / PT, t = bt % PT;
    const int n0 = chunk * 32;

    for (int idx = tid; idx < 4096; idx += 256) {
        int e = idx >> 6, c = idx & 63;
        wqT[c * 65 + e] = Wq[idx];
        wkT[c * 68 + e] = Wk[idx];
    }
    if (tid < 64) { bqs[tid] = bq[tid]; bks[tid] = bk[tid]; }
    for (int idx = tid; idx < 2048; idx += 256) {
        int c = idx >> 5, nl = idx & 31;
        int n = n0 + nl;
        xs[c][nl] = (n < PN) ? x[((b * PC + c) * PT + t) * PN + n] : 0.f;
    }
    __syncthreads();

    // ---- Q: thread owns e = tid&63, 8 consecutive rows nl = (tid>>6)*8 + j
    {
        const int e = tid & 63;
        const int nlb = (tid >> 6) * 8;
        float acc[8];
        #pragma unroll
        for (int j = 0; j < 8; ++j) acc[j] = bqs[e];
        #pragma unroll
        for (int c = 0; c < 64; ++c) {
            float w = wqT[c * 65 + e];
            const float4* xp4 = (const float4*)&xs[c][nlb];
            float4 x0 = xp4[0], x1 = xp4[1];
            acc[0] = fmaf(x0.x, w, acc[0]);
            acc[1] = fmaf(x0.y, w, acc[1]);
            acc[2] = fmaf(x0.z, w, acc[2]);
            acc[3] = fmaf(x0.w, w, acc[3]);
            acc[4] = fmaf(x1.x, w, acc[4]);
            acc[5] = fmaf(x1.y, w, acc[5]);
            acc[6] = fmaf(x1.z, w, acc[6]);
            acc[7] = fmaf(x1.w, w, acc[7]);
        }
        #pragma unroll
        for (int j = 0; j < 8; ++j) {
            int n = n0 + nlb + j;
            if (n < PN) qws[(bt * PN + n) * 64 + e] = acc[j];
        }
    }
    // ---- K: thread owns nl = tid&31, 8 consecutive e = (tid>>5)*8 + j
    {
        const int nl = tid & 31;
        const int eb = (tid >> 5) * 8;
        float acc[8];
        #pragma unroll
        for (int j = 0; j < 8; ++j) acc[j] = bks[eb + j];
        #pragma unroll
        for (int c = 0; c < 64; ++c) {
            float xv = xs[c][nl];
            const float4* wp4 = (const float4*)&wkT[c * 68 + eb];
            float4 w0 = wp4[0], w1 = wp4[1];
            acc[0] = fmaf(xv, w0.x, acc[0]);
            acc[1] = fmaf(xv, w0.y, acc[1]);
            acc[2] = fmaf(xv, w0.z, acc[2]);
            acc[3] = fmaf(xv, w0.w, acc[3]);
            acc[4] = fmaf(xv, w1.x, acc[4]);
            acc[5] = fmaf(xv, w1.y, acc[5]);
            acc[6] = fmaf(xv, w1.z, acc[6]);
            acc[7] = fmaf(xv, w1.w, acc[7]);
        }
        int n = n0 + nl;
        if (n < PN) {
            #pragma unroll
            for (int j = 0; j < 8; ++j)
                kws[(bt * 64 + eb + j) * NPAD + n] = f32_to_bf16(acc[j]);
        }
    }
}

// ---------------------------------------------------------------------------
// Kernel B: scores = Q K^T / sqrt(8), mask, softmax over m, write out.
// Grid: 96 (b,t) * 10 chunks of 32 rows. Block 256 (4 waves, 8 rows/wave).
// Each lane owns columns m = lane + 64*j, j = 0..4.
// ---------------------------------------------------------------------------
__global__ __launch_bounds__(256) void attn_kernel(
    const float* __restrict__ qws,
    const unsigned short* __restrict__ kws,
    const int* __restrict__ mask,
    float* __restrict__ out)
{
    __shared__ unsigned short kT[64 * NPAD];  // 40 KB, [c][m]
    __shared__ float qs[32][64];              // 8 KB

    const int tid = threadIdx.x;
    const int lane = tid & 63;
    const int wv = tid >> 6;
    const int chunk = blockIdx.x % 10;
    const int bt = blockIdx.x / 10;
    const int b = bt / PT;
    const int n0 = chunk * 32;

    // stage K^T tile (flat copy, both sides 16B aligned)
    {
        const uint4* src = (const uint4*)(kws + bt * 64 * NPAD);
        uint4* dst = (uint4*)kT;
        #pragma unroll
        for (int i = 0; i < 10; ++i) dst[tid + 256 * i] = src[tid + 256 * i];
    }
    // stage 32 q rows (tail block reads a little past qws into kws region of ws: benign)
    {
        const float4* src = (const float4*)(qws + (bt * PN + n0) * 64);
        float4* dst = (float4*)&qs[0][0];
        dst[tid] = src[tid];
        dst[tid + 256] = src[tid + 256];
    }
    __syncthreads();

    float acc[8][5];
    #pragma unroll
    for (int r = 0; r < 8; ++r)
        #pragma unroll
        for (int j = 0; j < 5; ++j) acc[r][j] = 0.f;

    for (int c = 0; c < 64; c += 4) {
        float kv[4][5];
        #pragma unroll
        for (int cc = 0; cc < 4; ++cc)
            #pragma unroll
            for (int j = 0; j < 5; ++j)
                kv[cc][j] = bf16_to_f32(kT[(c + cc) * NPAD + lane + 64 * j]);
        #pragma unroll
        for (int r = 0; r < 8; ++r) {
            const float4 qv = *(const float4*)&qs[wv * 8 + r][c];
            #pragma unroll
            for (int j = 0; j < 5; ++j) {
                acc[r][j] = fmaf(qv.x, kv[0][j], acc[r][j]);
                acc[r][j] = fmaf(qv.y, kv[1][j], acc[r][j]);
                acc[r][j] = fmaf(qv.z, kv[2][j], acc[r][j]);
                acc[r][j] = fmaf(qv.w, kv[3][j], acc[r][j]);
            }
        }
    }

    // softmax per row
    #pragma unroll
    for (int r = 0; r < 8; ++r) {
        const int n = n0 + wv * 8 + r;
        if (n >= PN) break;   // wave-uniform
        const int* mrow = mask + (b * PN + n) * PN;
        float s[5];
        #pragma unroll
        for (int j = 0; j < 5; ++j) {
            const int m = lane + 64 * j;
            if (j < 4 || m < PN) {
                s[j] = (mrow[m] != 0) ? acc[r][j] * SCALE : -1e9f;
            } else {
                s[j] = -INFINITY;   // padding columns
            }
        }
        float mx = s[0];
        #pragma unroll
        for (int j = 1; j < 5; ++j) mx = fmaxf(mx, s[j]);
        #pragma unroll
        for (int off = 32; off > 0; off >>= 1) mx = fmaxf(mx, __shfl_xor(mx, off));
        float sum = 0.f;
        #pragma unroll
        for (int j = 0; j < 5; ++j) { s[j] = __expf(s[j] - mx); sum += s[j]; }
        #pragma unroll
        for (int off = 32; off > 0; off >>= 1) sum += __shfl_xor(sum, off);
        const float inv = 1.0f / sum;
        float* orow = out + (bt * PN + n) * PN;
        #pragma unroll
        for (int j = 0; j < 5; ++j) {
            const int m = lane + 64 * j;
            if (j < 4 || m < PN) orow[m] = s[j] * inv;
        }
    }
}

extern "C" void kernel_launch(void* const* d_in, const int* in_sizes, int n_in,
                              void* d_out, int out_size, void* d_ws, size_t ws_size,
                              hipStream_t stream) {
    const float* x  = (const float*)d_in[0];
    const int* mask = (const int*)d_in[1];
    const float* Wq = (const float*)d_in[2];
    const float* bq = (const float*)d_in[3];
    const float* Wk = (const float*)d_in[4];
    const float* bk = (const float*)d_in[5];
    float* out = (float*)d_out;

    // workspace layout: qws fp32 [96*307*64], then kws bf16 [96*64*NPAD]
    float* qws = (float*)d_ws;
    unsigned short* kws = (unsigned short*)((char*)d_ws + (size_t)96 * PN * 64 * sizeof(float));

    qk_proj_kernel<<<dim3(96 * 10), dim3(256), 0, stream>>>(x, Wq, bq, Wk, bk, qws, kws);
    attn_kernel<<<dim3(96 * 10), dim3(256), 0, stream>>>(qws, kws, mask, out);
}

// Round 2
// 112.111 us; speedup vs baseline: 1.6980x; 1.6980x over previous
//
#include <hip/hip_runtime.h>
#include <math.h>

// Problem constants
#define PB 8
#define PT 12
#define PN 307
#define NP 320                      // padded N (rows and cols) for MFMA tiling
#define SCALE 0.35355339059327373f  // 1/sqrt(8)

typedef short bf16x8 __attribute__((ext_vector_type(8)));
typedef float f32x4  __attribute__((ext_vector_type(4)));

__device__ __forceinline__ unsigned short f32_to_bf16(float v) {
    unsigned u = __float_as_uint(v);
    u += 0x7FFFu + ((u >> 16) & 1u);   // RNE
    return (unsigned short)(u >> 16);
}

// ---------------------------------------------------------------------------
// Kernel A: Q/K projection -> bf16, row-major [bt][NP][64], pad rows zeroed.
// Grid: 96 bt * 5 chunks of 64 rows. Block 256.
// Each thread: e = tid&63, 16 rows starting at (tid>>6)*16. 32 fp32 accs.
// ---------------------------------------------------------------------------
__global__ __launch_bounds__(256) void qk_proj_kernel(
    const float* __restrict__ x,
    const float* __restrict__ Wq, const float* __restrict__ bq,
    const float* __restrict__ Wk, const float* __restrict__ bk,
    unsigned short* __restrict__ qws, unsigned short* __restrict__ kws)
{
    __shared__ float wqT[64 * 65];   // [c][e], stride 65: store banks (c+e)%32, load banks e%32 (2-way=free)
    __shared__ float wkT[64 * 65];
    __shared__ float xs[64][68];     // [c][nl], stride 68 keeps float4 alignment

    const int tid = threadIdx.x;
    const int chunk = blockIdx.x % 5;
    const int bt = blockIdx.x / 5;
    const int b = bt / PT, t = bt % PT;
    const int n0 = chunk * 64;

    for (int idx = tid; idx < 4096; idx += 256) {
        int e = idx >> 6, c = idx & 63;
        wqT[c * 65 + e] = Wq[idx];
        wkT[c * 65 + e] = Wk[idx];
    }
    for (int idx = tid; idx < 4096; idx += 256) {
        int c = idx >> 6, nl = idx & 63;     // lanes consecutive in nl -> coalesced 256B
        int n = n0 + nl;
        xs[c][nl] = (n < PN) ? x[((b * 64 + c) * PT + t) * PN + n] : 0.f;
    }
    __syncthreads();

    const int e  = tid & 63;
    const int rg = (tid >> 6) * 16;

    float accq[16], acck[16];
    const float bqv = bq[e], bkv = bk[e];
    #pragma unroll
    for (int j = 0; j < 16; ++j) { accq[j] = bqv; acck[j] = bkv; }

    #pragma unroll 4
    for (int c = 0; c < 64; ++c) {
        const float wq = wqT[c * 65 + e];
        const float wk = wkT[c * 65 + e];
        const float4* xp = (const float4*)&xs[c][rg];   // broadcast b128 reads
        float4 x0 = xp[0], x1 = xp[1], x2 = xp[2], x3 = xp[3];
        float xr[16] = {x0.x, x0.y, x0.z, x0.w, x1.x, x1.y, x1.z, x1.w,
                        x2.x, x2.y, x2.z, x2.w, x3.x, x3.y, x3.z, x3.w};
        #pragma unroll
        for (int j = 0; j < 16; ++j) {
            accq[j] = fmaf(xr[j], wq, accq[j]);
            acck[j] = fmaf(xr[j], wk, acck[j]);
        }
    }

    #pragma unroll
    for (int j = 0; j < 16; ++j) {
        const int n = n0 + rg + j;
        const bool v = (n < PN);
        // lanes e=0..63 consecutive -> 128B contiguous store per row
        qws[((size_t)bt * NP + n) * 64 + e] = v ? f32_to_bf16(accq[j]) : (unsigned short)0;
        kws[((size_t)bt * NP + n) * 64 + e] = v ? f32_to_bf16(acck[j]) : (unsigned short)0;
    }
}

// ---------------------------------------------------------------------------
// Kernel B: S = Q K^T / sqrt(8) via MFMA, mask, softmax over m, store.
// Grid: 96 bt * 5 chunks of 64 rows. Block 256 = 4 waves; wave owns 16 rows
// x 320 cols = 20 C-tiles of 16x16. No LDS, no barriers: fragments loaded
// straight from global as ushort8 (A/B layout: idx=lane&15, k=(lane>>4)*8+j).
// ---------------------------------------------------------------------------
__global__ __launch_bounds__(256) void attn_kernel(
    const unsigned short* __restrict__ qws,
    const unsigned short* __restrict__ kws,
    const int* __restrict__ mask,
    float* __restrict__ out)
{
    const int tid  = threadIdx.x;
    const int lane = tid & 63;
    const int wv   = tid >> 6;
    const int chunk = blockIdx.x % 5;
    const int bt    = blockIdx.x / 5;
    const int b     = bt / PT;
    const int n0    = chunk * 64 + wv * 16;  // wave's first row
    const int rlo   = lane & 15;             // A-row / B-col / C-col within tile
    const int kq    = lane >> 4;             // quad

    f32x4 acc[20] = {};

    const bf16x8* qp = (const bf16x8*)(qws + ((size_t)bt * NP + n0 + rlo) * 64 + kq * 8);
    const unsigned short* kbase0 = kws + ((size_t)bt * NP + rlo) * 64 + kq * 8;

    #pragma unroll
    for (int ks = 0; ks < 2; ++ks) {
        const bf16x8 afr = qp[ks * 4];                       // +32 halfwords per kstep
        const unsigned short* kb = kbase0 + ks * 32;
        #pragma unroll
        for (int ct = 0; ct < 20; ++ct) {
            const bf16x8 bfr = *(const bf16x8*)(kb + (size_t)ct * 16 * 64);
            acc[ct] = __builtin_amdgcn_mfma_f32_16x16x32_bf16(afr, bfr, acc[ct], 0, 0, 0);
        }
    }

    // ---- softmax in C layout: elem (ct, r) = S[n0 + kq*4 + r][ct*16 + rlo]
    float mx[4] = {-INFINITY, -INFINITY, -INFINITY, -INFINITY};
    #pragma unroll
    for (int ct = 0; ct < 20; ++ct) {
        const int m = ct * 16 + rlo;
        const bool mval = (m < PN);
        #pragma unroll
        for (int r = 0; r < 4; ++r) {
            const int n  = n0 + kq * 4 + r;
            const int nn = (n < PN) ? n : (PN - 1);          // clamp to stay in-bounds
            float s;
            if (mval) {
                const int mk = mask[((size_t)b * PN + nn) * PN + m];
                s = mk ? acc[ct][r] * SCALE : -1e9f;
            } else {
                s = -INFINITY;                               // pad columns
            }
            acc[ct][r] = s;
            mx[r] = fmaxf(mx[r], s);
        }
    }
    #pragma unroll
    for (int off = 1; off <= 8; off <<= 1) {
        #pragma unroll
        for (int r = 0; r < 4; ++r) mx[r] = fmaxf(mx[r], __shfl_xor(mx[r], off));
    }

    float sum[4] = {0.f, 0.f, 0.f, 0.f};
    #pragma unroll
    for (int ct = 0; ct < 20; ++ct) {
        #pragma unroll
        for (int r = 0; r < 4; ++r) {
            const float p = __expf(acc[ct][r] - mx[r]);
            acc[ct][r] = p;
            sum[r] += p;
        }
    }
    #pragma unroll
    for (int off = 1; off <= 8; off <<= 1) {
        #pragma unroll
        for (int r = 0; r < 4; ++r) sum[r] += __shfl_xor(sum[r], off);
    }
    float inv[4];
    #pragma unroll
    for (int r = 0; r < 4; ++r) inv[r] = 1.0f / sum[r];

    #pragma unroll
    for (int ct = 0; ct < 20; ++ct) {
        const int m = ct * 16 + rlo;
        if (m < PN) {
            #pragma unroll
            for (int r = 0; r < 4; ++r) {
                const int n = n0 + kq * 4 + r;
                if (n < PN)
                    out[((size_t)bt * PN + n) * PN + m] = acc[ct][r] * inv[r];
            }
        }
    }
}

extern "C" void kernel_launch(void* const* d_in, const int* in_sizes, int n_in,
                              void* d_out, int out_size, void* d_ws, size_t ws_size,
                              hipStream_t stream) {
    const float* x  = (const float*)d_in[0];
    const int* mask = (const int*)d_in[1];
    const float* Wq = (const float*)d_in[2];
    const float* bq = (const float*)d_in[3];
    const float* Wk = (const float*)d_in[4];
    const float* bk = (const float*)d_in[5];
    float* out = (float*)d_out;

    // workspace: qws bf16 [96][320][64], kws bf16 [96][320][64]  (7.86 MB total)
    unsigned short* qws = (unsigned short*)d_ws;
    unsigned short* kws = qws + (size_t)96 * NP * 64;

    qk_proj_kernel<<<dim3(96 * 5), dim3(256), 0, stream>>>(x, Wq, bq, Wk, bk, qws, kws);
    attn_kernel<<<dim3(96 * 5), dim3(256), 0, stream>>>(qws, kws, mask, out);
}